// Round 1
// baseline (775.593 us; speedup 1.0000x reference)
//
#include <hip/hip_runtime.h>
#include <math.h>

// Problem: B=8, N=1024, ME=1024, D=1024, fp32.
// a = sigmoid(z @ M @ e^T); A = softmax(a, axis=N); e_out = A @ e.
// Outputs concatenated: e_out [B,N,D] then A [B,N,ME].

#define TILE 128
#define KT 8

// Tiled fp32 GEMM: C[b] = A[b] (Mrows x K, row-major) * op(B[b])
//   BT=true : B is (Ncols x K) row-major, op(B) = B^T   (NT gemm)
//   BT=false: B is (K x Ncols) row-major                (NN gemm)
// EPI: 0 = plain store, 1 = store exp(sigmoid(x))
template<bool BT, int EPI>
__global__ __launch_bounds__(256) void gemm_kernel(
    const float* __restrict__ A, const float* __restrict__ B,
    float* __restrict__ C,
    long long sA, long long sB, long long sC,
    int Mrows, int Ncols, int K)
{
    __shared__ float As[KT][TILE + 4];
    __shared__ float Bs[KT][TILE + 4];

    const int bz = blockIdx.z;
    A += (long long)bz * sA;
    B += (long long)bz * sB;
    C += (long long)bz * sC;

    const int tid  = threadIdx.x;
    const int row0 = blockIdx.y * TILE;
    const int col0 = blockIdx.x * TILE;

    // A-tile (and BT B-tile) loader: 128 rows x 8 k; thread -> row=tid/2, k-quad=tid%2
    const int ld_r  = tid >> 1;
    const int ld_k4 = (tid & 1) * 4;
    // NN B-tile loader: 8 k-rows x 128 cols
    const int bn_k  = tid >> 5;
    const int bn_c4 = (tid & 31) * 4;

    const int tx = tid & 15, ty = tid >> 4;
    const int c0 = tx * 4, c1 = c0 + 64;
    const int r0 = ty * 4, r1 = r0 + 64;

    float acc[8][8];
#pragma unroll
    for (int i = 0; i < 8; i++)
#pragma unroll
        for (int j = 0; j < 8; j++) acc[i][j] = 0.f;

    for (int k0 = 0; k0 < K; k0 += KT) {
        float4 av = *(const float4*)(A + (long long)(row0 + ld_r) * K + k0 + ld_k4);
        float4 bv;
        if (BT) bv = *(const float4*)(B + (long long)(col0 + ld_r) * K + k0 + ld_k4);
        else    bv = *(const float4*)(B + (long long)(k0 + bn_k) * Ncols + col0 + bn_c4);

        __syncthreads();
        // A tile: transpose-store As[k][row]
        As[ld_k4 + 0][ld_r] = av.x;
        As[ld_k4 + 1][ld_r] = av.y;
        As[ld_k4 + 2][ld_r] = av.z;
        As[ld_k4 + 3][ld_r] = av.w;
        if (BT) {
            Bs[ld_k4 + 0][ld_r] = bv.x;
            Bs[ld_k4 + 1][ld_r] = bv.y;
            Bs[ld_k4 + 2][ld_r] = bv.z;
            Bs[ld_k4 + 3][ld_r] = bv.w;
        } else {
            *(float4*)&Bs[bn_k][bn_c4] = bv;
        }
        __syncthreads();

#pragma unroll
        for (int kk = 0; kk < KT; kk++) {
            float4 a0 = *(const float4*)&As[kk][r0];
            float4 a1 = *(const float4*)&As[kk][r1];
            float4 b0 = *(const float4*)&Bs[kk][c0];
            float4 b1 = *(const float4*)&Bs[kk][c1];
            float ar[8] = {a0.x, a0.y, a0.z, a0.w, a1.x, a1.y, a1.z, a1.w};
            float br[8] = {b0.x, b0.y, b0.z, b0.w, b1.x, b1.y, b1.z, b1.w};
#pragma unroll
            for (int i = 0; i < 8; i++)
#pragma unroll
                for (int j = 0; j < 8; j++)
                    acc[i][j] += ar[i] * br[j];
        }
    }

#pragma unroll
    for (int i = 0; i < 8; i++) {
        const int rr = (i < 4) ? (r0 + i) : (r1 + i - 4);
        float* crow = C + (long long)(row0 + rr) * Ncols + col0;
        float v[8];
#pragma unroll
        for (int j = 0; j < 8; j++) v[j] = acc[i][j];
        if (EPI == 1) {
#pragma unroll
            for (int j = 0; j < 8; j++) {
                float s = 1.0f / (1.0f + __expf(-v[j]));
                v[j] = __expf(s);
            }
        }
        *(float4*)(crow + c0) = make_float4(v[0], v[1], v[2], v[3]);
        *(float4*)(crow + c1) = make_float4(v[4], v[5], v[6], v[7]);
    }
}

// Partial column sums of P [B,N,ME] over N, atomically accumulated into sums[B*ME].
__global__ __launch_bounds__(256) void colsum_kernel(
    const float* __restrict__ P, float* __restrict__ sums,
    int Nn, int Mm, int chunk)
{
    const int g = blockIdx.x * 256 + threadIdx.x;   // 0 .. B*Mm-1
    const int b = g >> 10;                          // Mm = 1024
    const int m = g & 1023;
    const int n0 = blockIdx.y * chunk;
    const float* p = P + (long long)b * Nn * Mm + (long long)n0 * Mm + m;
    float s0 = 0.f, s1 = 0.f, s2 = 0.f, s3 = 0.f;
    for (int n = 0; n < chunk; n += 4) {
        s0 += p[(long long)(n + 0) * Mm];
        s1 += p[(long long)(n + 1) * Mm];
        s2 += p[(long long)(n + 2) * Mm];
        s3 += p[(long long)(n + 3) * Mm];
    }
    atomicAdd(&sums[g], (s0 + s1) + (s2 + s3));
}

// P[b,n,m] /= sums[b,m], in place (float4 per thread).
__global__ __launch_bounds__(256) void scale_kernel(
    float* __restrict__ P, const float* __restrict__ sums)
{
    const long long i4 = (long long)blockIdx.x * 256 + threadIdx.x;
    const long long base = i4 * 4;
    const int b = (int)(base >> 20);          // N*ME = 2^20
    const int col = (int)(base & 1023);       // ME = 1024
    float4 v = *(float4*)(P + base);
    const float4 s = *(const float4*)(sums + (b << 10) + col);
    v.x /= s.x; v.y /= s.y; v.z /= s.z; v.w /= s.w;
    *(float4*)(P + base) = v;
}

extern "C" void kernel_launch(void* const* d_in, const int* in_sizes, int n_in,
                              void* d_out, int out_size, void* d_ws, size_t ws_size,
                              hipStream_t stream)
{
    const int B = 8, N = 1024, ME = 1024, D = 1024;
    const float* z = (const float*)d_in[0];   // [B,N,D]
    const float* e = (const float*)d_in[1];   // [B,ME,D]
    const float* M = (const float*)d_in[2];   // [D,D]
    float* out   = (float*)d_out;
    float* e_out = out;                        // [B,N,D]
    float* Aout  = out + (long long)B * N * D; // [B,N,ME]; holds P then A

    float* zM   = (float*)d_ws;                               // [B,N,D] 32 MB
    float* sums = (float*)((char*)d_ws + (size_t)B * N * D * 4); // [B,ME] 32 KB

    // 1) zM = z @ M   (flatten batch: 8192 x 1024 x 1024, NN)
    gemm_kernel<false, 0><<<dim3(ME / TILE, (B * N) / TILE, 1), 256, 0, stream>>>(
        z, M, zM, 0, 0, 0, B * N, D, D);

    // 2) P = exp(sigmoid(zM @ e^T)) per batch (NT)
    gemm_kernel<true, 1><<<dim3(ME / TILE, N / TILE, B), 256, 0, stream>>>(
        zM, e, Aout, (long long)N * D, (long long)ME * D, (long long)N * ME,
        N, ME, D);

    // 3) softmax over N: column sums then scale in place
    hipMemsetAsync(sums, 0, (size_t)B * ME * sizeof(float), stream);
    colsum_kernel<<<dim3((B * ME) / 256, 8), 256, 0, stream>>>(Aout, sums, N, ME, N / 8);
    scale_kernel<<<dim3((B * N * ME / 4) / 256), 256, 0, stream>>>(Aout, sums);

    // 4) e_out = A @ e per batch (NN)
    gemm_kernel<false, 0><<<dim3(D / TILE, N / TILE, B), 256, 0, stream>>>(
        Aout, e, e_out, (long long)N * ME, (long long)ME * D, (long long)N * D,
        N, D, ME);
}

// Round 2
// 319.352 us; speedup vs baseline: 2.4286x; 2.4286x over previous
//
#include <hip/hip_runtime.h>
#include <math.h>
#include <stdint.h>

// Problem: B=8, N=1024, ME=1024, D=1024, fp32 in/out.
// a = sigmoid(z @ M @ e^T); A = softmax(a, axis=N); e_out = A @ e.
// Outputs concatenated: e_out [B,N,D] then A [B,N,ME].
//
// Fast path: split-bf16 MFMA. x = hi + lo (bf16 each); x*y ~= hi*hi + hi*lo + lo*hi,
// accumulated in fp32 MFMA. Error ~2^-17 relative per product — enough for the
// sigmoid(a) sensitivity (need |da| <= ~0.08 on a~N(0,1024^2)).
// Fallback path (ws too small): round-1 fp32 VALU GEMM.

typedef __bf16 bf16_8 __attribute__((ext_vector_type(8)));
typedef __bf16 bf16_4 __attribute__((ext_vector_type(4)));
typedef float  f32_4  __attribute__((ext_vector_type(4)));

// ---------------------------------------------------------------------------
// Async global->LDS 16B helper (wave-uniform LDS base + lane*16 semantics).
__device__ __forceinline__ void gload_lds16(const __bf16* g, __bf16* l) {
    __builtin_amdgcn_global_load_lds(
        (const __attribute__((address_space(1))) void*)g,
        (__attribute__((address_space(3))) void*)l,
        16, 0, 0);
}

__device__ __forceinline__ int swz(int r) { return (r ^ (r >> 2)) & 3; }

// Stage a 128x32 bf16 tile (rows = M/N dim, 32 = K chunk) into LDS.
// LDS layout: row-major 32 bf16/row, k-chunk slot s of row r holds global
// k-chunk (s ^ swz(r)) — XOR swizzle so frag ds_read_b128 is 2-way (free).
__device__ __forceinline__ void stage_tile(const __bf16* __restrict__ g, int ldK,
                                           int k0, __bf16* lds, int w, int lane) {
#pragma unroll
    for (int p = 0; p < 2; ++p) {
        const int row = w * 16 + p * 64 + (lane >> 2);
        const int kq  = (lane & 3) ^ swz(row);
        const __bf16* src = g + (long long)row * ldK + k0 + kq * 8;
        __bf16* dst = lds + (w * 16 + p * 64) * 32;   // wave-uniform
        gload_lds16(src, dst);
    }
}

// NT GEMM: C[Mrows x Ncols] = A[Mrows x K] * B[Ncols x K]^T, bf16 inputs,
// fp32 MFMA accumulate. SPLIT=1: also Alo/Blo, 3 MFMAs per tile-pair.
// EPI 0: store fp32 C.  EPI 1: store exp(sigmoid(x)) fp32.  EPI 2: store hi/lo bf16.
template<int SPLIT, int EPI>
__global__ __launch_bounds__(256) void mfma_gemm_nt(
    const __bf16* __restrict__ Ahi, const __bf16* __restrict__ Alo,
    const __bf16* __restrict__ Bhi, const __bf16* __restrict__ Blo,
    float* __restrict__ C, __bf16* __restrict__ Chi, __bf16* __restrict__ Clo,
    long long sA, long long sB, long long sC, int Ncols, int K)
{
    __shared__ __bf16 sAh[128 * 32];
    __shared__ __bf16 sBh[128 * 32];
    __shared__ __bf16 sAl[128 * 32];
    __shared__ __bf16 sBl[128 * 32];

    const int tid  = threadIdx.x;
    const int lane = tid & 63;
    const int w    = tid >> 6;
    const long long bz = blockIdx.z;

    const __bf16* pAh = Ahi + bz * sA + (long long)(blockIdx.y * 128) * K;
    const __bf16* pBh = Bhi + bz * sB + (long long)(blockIdx.x * 128) * K;
    const __bf16* pAl = SPLIT ? (Alo + bz * sA + (long long)(blockIdx.y * 128) * K) : nullptr;
    const __bf16* pBl = SPLIT ? (Blo + bz * sB + (long long)(blockIdx.x * 128) * K) : nullptr;

    const int fr = lane & 15;   // fragment row/col within 16
    const int q  = lane >> 4;   // k-quad 0..3
    const int wr = (w >> 1) * 64;
    const int wc = (w & 1) * 64;

    f32_4 acc[4][4];
#pragma unroll
    for (int i = 0; i < 4; ++i)
#pragma unroll
        for (int j = 0; j < 4; ++j) acc[i][j] = (f32_4){0.f, 0.f, 0.f, 0.f};

    for (int k0 = 0; k0 < K; k0 += 32) {
        stage_tile(pAh, K, k0, sAh, w, lane);
        stage_tile(pBh, K, k0, sBh, w, lane);
        if (SPLIT) {
            stage_tile(pAl, K, k0, sAl, w, lane);
            stage_tile(pBl, K, k0, sBl, w, lane);
        }
        __syncthreads();   // drains vmcnt (global_load_lds) + orders LDS

        bf16_8 ah[4], bh[4], al[4], bl[4];
#pragma unroll
        for (int i = 0; i < 4; ++i) {
            const int r = wr + 16 * i + fr;
            const int offA = r * 32 + ((q ^ swz(r)) * 8);
            ah[i] = *(const bf16_8*)(sAh + offA);
            if (SPLIT) al[i] = *(const bf16_8*)(sAl + offA);
            const int c = wc + 16 * i + fr;
            const int offB = c * 32 + ((q ^ swz(c)) * 8);
            bh[i] = *(const bf16_8*)(sBh + offB);
            if (SPLIT) bl[i] = *(const bf16_8*)(sBl + offB);
        }
#pragma unroll
        for (int i = 0; i < 4; ++i)
#pragma unroll
            for (int j = 0; j < 4; ++j) {
                acc[i][j] = __builtin_amdgcn_mfma_f32_16x16x32_bf16(ah[i], bh[j], acc[i][j], 0, 0, 0);
                if (SPLIT) {
                    acc[i][j] = __builtin_amdgcn_mfma_f32_16x16x32_bf16(ah[i], bl[j], acc[i][j], 0, 0, 0);
                    acc[i][j] = __builtin_amdgcn_mfma_f32_16x16x32_bf16(al[i], bh[j], acc[i][j], 0, 0, 0);
                }
            }
        __syncthreads();   // protect LDS before next stage
    }

    // Epilogue. C/D layout (16x16x32): col = lane&15, row = (lane>>4)*4 + reg.
    const int row0 = blockIdx.y * 128 + wr;
    const int col0 = blockIdx.x * 128 + wc;
#pragma unroll
    for (int i = 0; i < 4; ++i)
#pragma unroll
        for (int j = 0; j < 4; ++j) {
            const int col = col0 + 16 * j + fr;
#pragma unroll
            for (int reg = 0; reg < 4; ++reg) {
                const int row = row0 + 16 * i + q * 4 + reg;
                float v = acc[i][j][reg];
                const long long idx = bz * sC + (long long)row * Ncols + col;
                if (EPI == 0) {
                    C[idx] = v;
                } else if (EPI == 1) {
                    float s = 1.0f / (1.0f + __expf(-v));
                    C[idx] = __expf(s);
                } else {
                    __bf16 h = (__bf16)v;
                    Chi[idx] = h;
                    Clo[idx] = (__bf16)(v - (float)h);
                }
            }
        }
}

// x -> hi = bf16(x), lo = bf16(x - hi); float4 per thread.
__global__ __launch_bounds__(256) void split2_kernel(
    const float* __restrict__ x, __bf16* __restrict__ hi, __bf16* __restrict__ lo)
{
    const long long i = (blockIdx.x * 256LL + threadIdx.x) * 4;
    float4 v = *(const float4*)(x + i);
    bf16_4 h, l;
    h[0] = (__bf16)v.x; l[0] = (__bf16)(v.x - (float)h[0]);
    h[1] = (__bf16)v.y; l[1] = (__bf16)(v.y - (float)h[1]);
    h[2] = (__bf16)v.z; l[2] = (__bf16)(v.z - (float)h[2]);
    h[3] = (__bf16)v.w; l[3] = (__bf16)(v.w - (float)h[3]);
    *(bf16_4*)(hi + i) = h;
    *(bf16_4*)(lo + i) = l;
}

// out[c*R + r] = in[r*C + c] (fp32 in, bf16 hi(+lo) out), batched via blockIdx.z.
__global__ __launch_bounds__(256) void transpose_split_kernel(
    const float* __restrict__ in, __bf16* __restrict__ hi, __bf16* __restrict__ lo,
    int R, int Cc, int doLo)
{
    __shared__ float t[32][33];
    const long long base = (long long)blockIdx.z * R * Cc;
    const int r0 = blockIdx.y * 32, c0 = blockIdx.x * 32;
    const int tx = threadIdx.x & 31, ty = threadIdx.x >> 5;  // ty 0..7
#pragma unroll
    for (int rr = ty; rr < 32; rr += 8)
        t[rr][tx] = in[base + (long long)(r0 + rr) * Cc + c0 + tx];
    __syncthreads();
#pragma unroll
    for (int cc = ty; cc < 32; cc += 8) {
        const float v = t[tx][cc];
        const long long o = base + (long long)(c0 + cc) * R + r0 + tx;
        __bf16 h = (__bf16)v;
        hi[o] = h;
        if (doLo) lo[o] = (__bf16)(v - (float)h);
    }
}

// Partial column sums of P [B,N,ME] over N into sums[B*ME] (atomic).
__global__ __launch_bounds__(256) void colsum_kernel(
    const float* __restrict__ P, float* __restrict__ sums, int Nn, int Mm, int chunk)
{
    const int g = blockIdx.x * 256 + threadIdx.x;
    const int b = g >> 10;
    const int m = g & 1023;
    const int n0 = blockIdx.y * chunk;
    const float* p = P + (long long)b * Nn * Mm + (long long)n0 * Mm + m;
    float s0 = 0.f, s1 = 0.f, s2 = 0.f, s3 = 0.f;
    for (int n = 0; n < chunk; n += 4) {
        s0 += p[(long long)(n + 0) * Mm];
        s1 += p[(long long)(n + 1) * Mm];
        s2 += p[(long long)(n + 2) * Mm];
        s3 += p[(long long)(n + 3) * Mm];
    }
    atomicAdd(&sums[g], (s0 + s1) + (s2 + s3));
}

// P /= colsum, in place; also emit bf16 copy for GEMM3.
__global__ __launch_bounds__(256) void scale2_kernel(
    float* __restrict__ P, const float* __restrict__ sums, __bf16* __restrict__ Pb)
{
    const long long base = (blockIdx.x * 256LL + threadIdx.x) * 4;
    const int b = (int)(base >> 20);
    const int col = (int)(base & 1023);
    float4 v = *(float4*)(P + base);
    const float4 s = *(const float4*)(sums + (b << 10) + col);
    v.x /= s.x; v.y /= s.y; v.z /= s.z; v.w /= s.w;
    *(float4*)(P + base) = v;
    bf16_4 h;
    h[0] = (__bf16)v.x; h[1] = (__bf16)v.y; h[2] = (__bf16)v.z; h[3] = (__bf16)v.w;
    *(bf16_4*)(Pb + base) = h;
}

// ---------------------------------------------------------------------------
// Fallback fp32 path (round-1 kernels, unchanged).
#define TILE 128
#define KT 8
template<bool BT, int EPI>
__global__ __launch_bounds__(256) void gemm_kernel(
    const float* __restrict__ A, const float* __restrict__ B, float* __restrict__ C,
    long long sA, long long sB, long long sC, int Mrows, int Ncols, int K)
{
    __shared__ float As[KT][TILE + 4];
    __shared__ float Bs[KT][TILE + 4];
    const int bz = blockIdx.z;
    A += (long long)bz * sA; B += (long long)bz * sB; C += (long long)bz * sC;
    const int tid = threadIdx.x;
    const int row0 = blockIdx.y * TILE, col0 = blockIdx.x * TILE;
    const int ld_r = tid >> 1, ld_k4 = (tid & 1) * 4;
    const int bn_k = tid >> 5, bn_c4 = (tid & 31) * 4;
    const int tx = tid & 15, ty = tid >> 4;
    const int c0 = tx * 4, c1 = c0 + 64, r0 = ty * 4, r1 = r0 + 64;
    float acc[8][8];
#pragma unroll
    for (int i = 0; i < 8; i++)
#pragma unroll
        for (int j = 0; j < 8; j++) acc[i][j] = 0.f;
    for (int k0 = 0; k0 < K; k0 += KT) {
        float4 av = *(const float4*)(A + (long long)(row0 + ld_r) * K + k0 + ld_k4);
        float4 bv;
        if (BT) bv = *(const float4*)(B + (long long)(col0 + ld_r) * K + k0 + ld_k4);
        else    bv = *(const float4*)(B + (long long)(k0 + bn_k) * Ncols + col0 + bn_c4);
        __syncthreads();
        As[ld_k4 + 0][ld_r] = av.x; As[ld_k4 + 1][ld_r] = av.y;
        As[ld_k4 + 2][ld_r] = av.z; As[ld_k4 + 3][ld_r] = av.w;
        if (BT) {
            Bs[ld_k4 + 0][ld_r] = bv.x; Bs[ld_k4 + 1][ld_r] = bv.y;
            Bs[ld_k4 + 2][ld_r] = bv.z; Bs[ld_k4 + 3][ld_r] = bv.w;
        } else {
            *(float4*)&Bs[bn_k][bn_c4] = bv;
        }
        __syncthreads();
#pragma unroll
        for (int kk = 0; kk < KT; kk++) {
            float4 a0 = *(const float4*)&As[kk][r0];
            float4 a1 = *(const float4*)&As[kk][r1];
            float4 b0 = *(const float4*)&Bs[kk][c0];
            float4 b1 = *(const float4*)&Bs[kk][c1];
            float ar[8] = {a0.x, a0.y, a0.z, a0.w, a1.x, a1.y, a1.z, a1.w};
            float br[8] = {b0.x, b0.y, b0.z, b0.w, b1.x, b1.y, b1.z, b1.w};
#pragma unroll
            for (int i = 0; i < 8; i++)
#pragma unroll
                for (int j = 0; j < 8; j++) acc[i][j] += ar[i] * br[j];
        }
    }
#pragma unroll
    for (int i = 0; i < 8; i++) {
        const int rr = (i < 4) ? (r0 + i) : (r1 + i - 4);
        float* crow = C + (long long)(row0 + rr) * Ncols + col0;
        float v[8];
#pragma unroll
        for (int j = 0; j < 8; j++) v[j] = acc[i][j];
        if (EPI == 1) {
#pragma unroll
            for (int j = 0; j < 8; j++) {
                float s = 1.0f / (1.0f + __expf(-v[j]));
                v[j] = __expf(s);
            }
        }
        *(float4*)(crow + c0) = make_float4(v[0], v[1], v[2], v[3]);
        *(float4*)(crow + c1) = make_float4(v[4], v[5], v[6], v[7]);
    }
}

__global__ __launch_bounds__(256) void scale_kernel(
    float* __restrict__ P, const float* __restrict__ sums)
{
    const long long base = (blockIdx.x * 256LL + threadIdx.x) * 4;
    const int b = (int)(base >> 20);
    const int col = (int)(base & 1023);
    float4 v = *(float4*)(P + base);
    const float4 s = *(const float4*)(sums + (b << 10) + col);
    v.x /= s.x; v.y /= s.y; v.z /= s.z; v.w /= s.w;
    *(float4*)(P + base) = v;
}

// ---------------------------------------------------------------------------
extern "C" void kernel_launch(void* const* d_in, const int* in_sizes, int n_in,
                              void* d_out, int out_size, void* d_ws, size_t ws_size,
                              hipStream_t stream)
{
    const int B = 8, N = 1024, ME = 1024, D = 1024;
    const float* z = (const float*)d_in[0];   // [B,N,D]
    const float* e = (const float*)d_in[1];   // [B,ME,D]
    const float* M = (const float*)d_in[2];   // [D,D]
    float* out   = (float*)d_out;
    float* e_out = out;                         // [B,N,D]
    float* Aout  = out + (long long)B * N * D;  // [B,N,ME]; holds P then A

    const size_t MB = 1024 * 1024;
    const size_t NEEDED = 100 * MB + (size_t)B * ME * sizeof(float);

    if (ws_size >= NEEDED) {
        char* W = (char*)d_ws;
        __bf16* z_hi  = (__bf16*)(W);
        __bf16* z_lo  = (__bf16*)(W + 16 * MB);
        __bf16* e_hi  = (__bf16*)(W + 32 * MB);
        __bf16* e_lo  = (__bf16*)(W + 48 * MB);
        __bf16* MT_hi = (__bf16*)(W + 64 * MB);
        __bf16* MT_lo = (__bf16*)(W + 66 * MB);
        __bf16* zM_hi = (__bf16*)(W + 68 * MB);
        __bf16* zM_lo = (__bf16*)(W + 84 * MB);
        float*  sums  = (float*)(W + 100 * MB);
        __bf16* A_bf  = z_hi;   // reused after GEMM1
        __bf16* eT    = z_lo;   // reused after GEMM1

        // Prep: splits + M transpose.
        split2_kernel<<<dim3((B * N * D / 4) / 256), 256, 0, stream>>>(z, z_hi, z_lo);
        split2_kernel<<<dim3((B * ME * D / 4) / 256), 256, 0, stream>>>(e, e_hi, e_lo);
        transpose_split_kernel<<<dim3(D / 32, D / 32, 1), 256, 0, stream>>>(
            M, MT_hi, MT_lo, D, D, 1);

        // GEMM1: zM = z @ M  (NT vs M^T), split in + split bf16 out. [8192x1024x1024]
        mfma_gemm_nt<1, 2><<<dim3(D / 128, (B * N) / 128, 1), 256, 0, stream>>>(
            z_hi, z_lo, MT_hi, MT_lo, nullptr, zM_hi, zM_lo, 0, 0, 0, D, D);

        // eT = bf16(e)^T per batch (for GEMM3), into z_lo's old region.
        transpose_split_kernel<<<dim3(D / 32, ME / 32, B), 256, 0, stream>>>(
            e, eT, nullptr, ME, D, 0);

        // GEMM2: P = exp(sigmoid(zM @ e^T)) per batch, fp32 out to Aout.
        mfma_gemm_nt<1, 1><<<dim3(ME / 128, N / 128, B), 256, 0, stream>>>(
            zM_hi, zM_lo, e_hi, e_lo, Aout, nullptr, nullptr,
            (long long)N * D, (long long)ME * D, (long long)N * ME, ME, D);

        // Softmax over N: colsum + scale (also emits bf16 A).
        hipMemsetAsync(sums, 0, (size_t)B * ME * sizeof(float), stream);
        colsum_kernel<<<dim3((B * ME) / 256, 8), 256, 0, stream>>>(Aout, sums, N, ME, N / 8);
        scale2_kernel<<<dim3((B * N * ME / 4) / 256), 256, 0, stream>>>(Aout, sums, A_bf);

        // GEMM3: e_out = A @ e per batch (NT vs eT), plain bf16.
        mfma_gemm_nt<0, 0><<<dim3(D / 128, N / 128, B), 256, 0, stream>>>(
            A_bf, nullptr, eT, nullptr, e_out, nullptr, nullptr,
            (long long)N * ME, (long long)D * ME, (long long)N * D, D, ME);
    } else {
        // fp32 fallback (round-1 path), needs 32 MB + 32 KB.
        float* zM   = (float*)d_ws;
        float* sums = (float*)((char*)d_ws + (size_t)B * N * D * 4);
        gemm_kernel<false, 0><<<dim3(ME / TILE, (B * N) / TILE, 1), 256, 0, stream>>>(
            z, M, zM, 0, 0, 0, B * N, D, D);
        gemm_kernel<true, 1><<<dim3(ME / TILE, N / TILE, B), 256, 0, stream>>>(
            zM, e, Aout, (long long)N * D, (long long)ME * D, (long long)N * ME, N, ME, D);
        hipMemsetAsync(sums, 0, (size_t)B * ME * sizeof(float), stream);
        colsum_kernel<<<dim3((B * ME) / 256, 8), 256, 0, stream>>>(Aout, sums, N, ME, N / 8);
        scale_kernel<<<dim3((B * N * ME / 4) / 256), 256, 0, stream>>>(Aout, sums);
        gemm_kernel<false, 0><<<dim3(D / TILE, N / TILE, B), 256, 0, stream>>>(
            Aout, e, e_out, (long long)N * ME, (long long)ME * D, (long long)N * D, N, D, ME);
    }
}

// Round 3
// 306.697 us; speedup vs baseline: 2.5289x; 1.0413x over previous
//
#include <hip/hip_runtime.h>
#include <math.h>
#include <stdint.h>

// Problem: B=8, N=1024, ME=1024, D=1024, fp32 in/out.
// a = sigmoid(z @ M @ e^T); A = softmax(a, axis=N); e_out = A @ e.
// Outputs concatenated: e_out [B,N,D] then A [B,N,ME].
//
// Fast path: split-bf16 MFMA (x = hi+lo; hi*hi + hi*lo + lo*hi in fp32 MFMA).
// Round 3: colsum fused into GEMM2 epilogue (atomics); e-transpose fused into
// e-split kernel; fewer launches.

typedef __bf16 bf16_8 __attribute__((ext_vector_type(8)));
typedef __bf16 bf16_4 __attribute__((ext_vector_type(4)));
typedef float  f32_4  __attribute__((ext_vector_type(4)));

// ---------------------------------------------------------------------------
__device__ __forceinline__ void gload_lds16(const __bf16* g, __bf16* l) {
    __builtin_amdgcn_global_load_lds(
        (const __attribute__((address_space(1))) void*)g,
        (__attribute__((address_space(3))) void*)l,
        16, 0, 0);
}

__device__ __forceinline__ int swz(int r) { return (r ^ (r >> 2)) & 3; }

// Stage a 128x32 bf16 tile into LDS (row-major 32 bf16/row, XOR k-chunk swizzle).
__device__ __forceinline__ void stage_tile(const __bf16* __restrict__ g, int ldK,
                                           int k0, __bf16* lds, int w, int lane) {
#pragma unroll
    for (int p = 0; p < 2; ++p) {
        const int row = w * 16 + p * 64 + (lane >> 2);
        const int kq  = (lane & 3) ^ swz(row);
        const __bf16* src = g + (long long)row * ldK + k0 + kq * 8;
        __bf16* dst = lds + (w * 16 + p * 64) * 32;   // wave-uniform
        gload_lds16(src, dst);
    }
}

// NT GEMM: C[Mrows x Ncols] = A[Mrows x K] * B[Ncols x K]^T, bf16 in, fp32 acc.
// SPLIT=1: hi/lo inputs, 3 MFMAs per tile-pair.
// EPI 0: store fp32. EPI 1: store exp(sigmoid(x)) fp32 + fused column-sum atomics.
// EPI 2: store hi/lo bf16.
template<int SPLIT, int EPI>
__global__ __launch_bounds__(256) void mfma_gemm_nt(
    const __bf16* __restrict__ Ahi, const __bf16* __restrict__ Alo,
    const __bf16* __restrict__ Bhi, const __bf16* __restrict__ Blo,
    float* __restrict__ C, __bf16* __restrict__ Chi, __bf16* __restrict__ Clo,
    float* __restrict__ sums,
    long long sA, long long sB, long long sC, int Ncols, int K)
{
    __shared__ __bf16 sAh[128 * 32];
    __shared__ __bf16 sBh[128 * 32];
    __shared__ __bf16 sAl[128 * 32];
    __shared__ __bf16 sBl[128 * 32];

    const int tid  = threadIdx.x;
    const int lane = tid & 63;
    const int w    = tid >> 6;
    const long long bz = blockIdx.z;

    const __bf16* pAh = Ahi + bz * sA + (long long)(blockIdx.y * 128) * K;
    const __bf16* pBh = Bhi + bz * sB + (long long)(blockIdx.x * 128) * K;
    const __bf16* pAl = SPLIT ? (Alo + bz * sA + (long long)(blockIdx.y * 128) * K) : nullptr;
    const __bf16* pBl = SPLIT ? (Blo + bz * sB + (long long)(blockIdx.x * 128) * K) : nullptr;

    const int fr = lane & 15;   // fragment row/col within 16
    const int q  = lane >> 4;   // k-quad 0..3
    const int wr = (w >> 1) * 64;
    const int wc = (w & 1) * 64;

    f32_4 acc[4][4];
#pragma unroll
    for (int i = 0; i < 4; ++i)
#pragma unroll
        for (int j = 0; j < 4; ++j) acc[i][j] = (f32_4){0.f, 0.f, 0.f, 0.f};

    for (int k0 = 0; k0 < K; k0 += 32) {
        stage_tile(pAh, K, k0, sAh, w, lane);
        stage_tile(pBh, K, k0, sBh, w, lane);
        if (SPLIT) {
            stage_tile(pAl, K, k0, sAl, w, lane);
            stage_tile(pBl, K, k0, sBl, w, lane);
        }
        __syncthreads();

        bf16_8 ah[4], bh[4], al[4], bl[4];
#pragma unroll
        for (int i = 0; i < 4; ++i) {
            const int r = wr + 16 * i + fr;
            const int offA = r * 32 + ((q ^ swz(r)) * 8);
            ah[i] = *(const bf16_8*)(sAh + offA);
            if (SPLIT) al[i] = *(const bf16_8*)(sAl + offA);
            const int c = wc + 16 * i + fr;
            const int offB = c * 32 + ((q ^ swz(c)) * 8);
            bh[i] = *(const bf16_8*)(sBh + offB);
            if (SPLIT) bl[i] = *(const bf16_8*)(sBl + offB);
        }
#pragma unroll
        for (int i = 0; i < 4; ++i)
#pragma unroll
            for (int j = 0; j < 4; ++j) {
                acc[i][j] = __builtin_amdgcn_mfma_f32_16x16x32_bf16(ah[i], bh[j], acc[i][j], 0, 0, 0);
                if (SPLIT) {
                    acc[i][j] = __builtin_amdgcn_mfma_f32_16x16x32_bf16(ah[i], bl[j], acc[i][j], 0, 0, 0);
                    acc[i][j] = __builtin_amdgcn_mfma_f32_16x16x32_bf16(al[i], bh[j], acc[i][j], 0, 0, 0);
                }
            }
        __syncthreads();
    }

    // Epilogue. C/D layout (16x16x32): col = lane&15, row = (lane>>4)*4 + reg.
    const int row0 = blockIdx.y * 128 + wr;
    const int col0 = blockIdx.x * 128 + wc;
    float cs[4] = {0.f, 0.f, 0.f, 0.f};
#pragma unroll
    for (int i = 0; i < 4; ++i)
#pragma unroll
        for (int j = 0; j < 4; ++j) {
            const int col = col0 + 16 * j + fr;
#pragma unroll
            for (int reg = 0; reg < 4; ++reg) {
                const int row = row0 + 16 * i + q * 4 + reg;
                float v = acc[i][j][reg];
                const long long idx = bz * sC + (long long)row * Ncols + col;
                if (EPI == 0) {
                    C[idx] = v;
                } else if (EPI == 1) {
                    float s = 1.0f / (1.0f + __expf(-v));
                    v = __expf(s);
                    C[idx] = v;
                    cs[j] += v;
                } else {
                    __bf16 h = (__bf16)v;
                    Chi[idx] = h;
                    Clo[idx] = (__bf16)(v - (float)h);
                }
            }
        }
    if (EPI == 1) {
        // Reduce column partials across the 4 k-quads (lanes fr, fr+16, fr+32, fr+48).
#pragma unroll
        for (int j = 0; j < 4; ++j) {
            float s = cs[j];
            s += __shfl_xor(s, 16, 64);
            s += __shfl_xor(s, 32, 64);
            if (lane < 16)
                atomicAdd(&sums[bz * Ncols + col0 + 16 * j + lane], s);
        }
    }
}

// x -> hi = bf16(x), lo = bf16(x - hi); float4 per thread.
__global__ __launch_bounds__(256) void split2_kernel(
    const float* __restrict__ x, __bf16* __restrict__ hi, __bf16* __restrict__ lo)
{
    const long long i = (blockIdx.x * 256LL + threadIdx.x) * 4;
    float4 v = *(const float4*)(x + i);
    bf16_4 h, l;
    h[0] = (__bf16)v.x; l[0] = (__bf16)(v.x - (float)h[0]);
    h[1] = (__bf16)v.y; l[1] = (__bf16)(v.y - (float)h[1]);
    h[2] = (__bf16)v.z; l[2] = (__bf16)(v.z - (float)h[2]);
    h[3] = (__bf16)v.w; l[3] = (__bf16)(v.w - (float)h[3]);
    *(bf16_4*)(hi + i) = h;
    *(bf16_4*)(lo + i) = l;
}

// Fused: e [B,ME,D] fp32 -> e_hi,e_lo [B,ME,D] bf16 (row-major) AND eT [B,D,ME] bf16.
// 64x64 tiles; LDS transpose with +1 padding.
__global__ __launch_bounds__(256) void splitT_e_kernel(
    const float* __restrict__ e, __bf16* __restrict__ hi, __bf16* __restrict__ lo,
    __bf16* __restrict__ eT, int ME, int D)
{
    __shared__ float t[64][65];
    const long long bb = blockIdx.z;
    const int m0 = blockIdx.y * 64, d0 = blockIdx.x * 64;
    const int tx = threadIdx.x & 15, ty = threadIdx.x >> 4;   // ty 0..15
#pragma unroll
    for (int i = 0; i < 4; ++i) {
        const int r = 16 * i + ty;
        const long long o = (bb * ME + m0 + r) * (long long)D + d0 + 4 * tx;
        float4 v = *(const float4*)(e + o);
        bf16_4 h, l;
        h[0] = (__bf16)v.x; l[0] = (__bf16)(v.x - (float)h[0]);
        h[1] = (__bf16)v.y; l[1] = (__bf16)(v.y - (float)h[1]);
        h[2] = (__bf16)v.z; l[2] = (__bf16)(v.z - (float)h[2]);
        h[3] = (__bf16)v.w; l[3] = (__bf16)(v.w - (float)h[3]);
        *(bf16_4*)(hi + o) = h;
        *(bf16_4*)(lo + o) = l;
        t[r][4 * tx + 0] = v.x;
        t[r][4 * tx + 1] = v.y;
        t[r][4 * tx + 2] = v.z;
        t[r][4 * tx + 3] = v.w;
    }
    __syncthreads();
#pragma unroll
    for (int i = 0; i < 4; ++i) {
        const int dloc = 16 * i + ty;
        bf16_4 p;
#pragma unroll
        for (int j = 0; j < 4; ++j) p[j] = (__bf16)t[4 * tx + j][dloc];
        const long long o = (bb * D + d0 + dloc) * (long long)ME + m0 + 4 * tx;
        *(bf16_4*)(eT + o) = p;
    }
}

// out[c*R + r] = in[r*C + c] (fp32 in, bf16 hi(+lo) out). Used for M only.
__global__ __launch_bounds__(256) void transpose_split_kernel(
    const float* __restrict__ in, __bf16* __restrict__ hi, __bf16* __restrict__ lo,
    int R, int Cc, int doLo)
{
    __shared__ float t[32][33];
    const long long base = (long long)blockIdx.z * R * Cc;
    const int r0 = blockIdx.y * 32, c0 = blockIdx.x * 32;
    const int tx = threadIdx.x & 31, ty = threadIdx.x >> 5;  // ty 0..7
#pragma unroll
    for (int rr = ty; rr < 32; rr += 8)
        t[rr][tx] = in[base + (long long)(r0 + rr) * Cc + c0 + tx];
    __syncthreads();
#pragma unroll
    for (int cc = ty; cc < 32; cc += 8) {
        const float v = t[tx][cc];
        const long long o = base + (long long)(c0 + cc) * R + r0 + tx;
        __bf16 h = (__bf16)v;
        hi[o] = h;
        if (doLo) lo[o] = (__bf16)(v - (float)h);
    }
}

// P /= colsum, in place; also emit bf16 copy for GEMM3.
__global__ __launch_bounds__(256) void scale2_kernel(
    float* __restrict__ P, const float* __restrict__ sums, __bf16* __restrict__ Pb)
{
    const long long base = (blockIdx.x * 256LL + threadIdx.x) * 4;
    const int b = (int)(base >> 20);
    const int col = (int)(base & 1023);
    float4 v = *(float4*)(P + base);
    const float4 s = *(const float4*)(sums + (b << 10) + col);
    v.x /= s.x; v.y /= s.y; v.z /= s.z; v.w /= s.w;
    *(float4*)(P + base) = v;
    bf16_4 h;
    h[0] = (__bf16)v.x; h[1] = (__bf16)v.y; h[2] = (__bf16)v.z; h[3] = (__bf16)v.w;
    *(bf16_4*)(Pb + base) = h;
}

// ---------------------------------------------------------------------------
// Fallback fp32 path (round-1 kernels).
#define TILE 128
#define KT 8
template<bool BT, int EPI>
__global__ __launch_bounds__(256) void gemm_kernel(
    const float* __restrict__ A, const float* __restrict__ B, float* __restrict__ C,
    long long sA, long long sB, long long sC, int Mrows, int Ncols, int K)
{
    __shared__ float As[KT][TILE + 4];
    __shared__ float Bs[KT][TILE + 4];
    const int bz = blockIdx.z;
    A += (long long)bz * sA; B += (long long)bz * sB; C += (long long)bz * sC;
    const int tid = threadIdx.x;
    const int row0 = blockIdx.y * TILE, col0 = blockIdx.x * TILE;
    const int ld_r = tid >> 1, ld_k4 = (tid & 1) * 4;
    const int bn_k = tid >> 5, bn_c4 = (tid & 31) * 4;
    const int tx = tid & 15, ty = tid >> 4;
    const int c0 = tx * 4, c1 = c0 + 64, r0 = ty * 4, r1 = r0 + 64;
    float acc[8][8];
#pragma unroll
    for (int i = 0; i < 8; i++)
#pragma unroll
        for (int j = 0; j < 8; j++) acc[i][j] = 0.f;
    for (int k0 = 0; k0 < K; k0 += KT) {
        float4 av = *(const float4*)(A + (long long)(row0 + ld_r) * K + k0 + ld_k4);
        float4 bv;
        if (BT) bv = *(const float4*)(B + (long long)(col0 + ld_r) * K + k0 + ld_k4);
        else    bv = *(const float4*)(B + (long long)(k0 + bn_k) * Ncols + col0 + bn_c4);
        __syncthreads();
        As[ld_k4 + 0][ld_r] = av.x; As[ld_k4 + 1][ld_r] = av.y;
        As[ld_k4 + 2][ld_r] = av.z; As[ld_k4 + 3][ld_r] = av.w;
        if (BT) {
            Bs[ld_k4 + 0][ld_r] = bv.x; Bs[ld_k4 + 1][ld_r] = bv.y;
            Bs[ld_k4 + 2][ld_r] = bv.z; Bs[ld_k4 + 3][ld_r] = bv.w;
        } else {
            *(float4*)&Bs[bn_k][bn_c4] = bv;
        }
        __syncthreads();
#pragma unroll
        for (int kk = 0; kk < KT; kk++) {
            float4 a0 = *(const float4*)&As[kk][r0];
            float4 a1 = *(const float4*)&As[kk][r1];
            float4 b0 = *(const float4*)&Bs[kk][c0];
            float4 b1 = *(const float4*)&Bs[kk][c1];
            float ar[8] = {a0.x, a0.y, a0.z, a0.w, a1.x, a1.y, a1.z, a1.w};
            float br[8] = {b0.x, b0.y, b0.z, b0.w, b1.x, b1.y, b1.z, b1.w};
#pragma unroll
            for (int i = 0; i < 8; i++)
#pragma unroll
                for (int j = 0; j < 8; j++) acc[i][j] += ar[i] * br[j];
        }
    }
#pragma unroll
    for (int i = 0; i < 8; i++) {
        const int rr = (i < 4) ? (r0 + i) : (r1 + i - 4);
        float* crow = C + (long long)(row0 + rr) * Ncols + col0;
        float v[8];
#pragma unroll
        for (int j = 0; j < 8; j++) v[j] = acc[i][j];
        if (EPI == 1) {
#pragma unroll
            for (int j = 0; j < 8; j++) {
                float s = 1.0f / (1.0f + __expf(-v[j]));
                v[j] = __expf(s);
            }
        }
        *(float4*)(crow + c0) = make_float4(v[0], v[1], v[2], v[3]);
        *(float4*)(crow + c1) = make_float4(v[4], v[5], v[6], v[7]);
    }
}

__global__ __launch_bounds__(256) void colsum_kernel(
    const float* __restrict__ P, float* __restrict__ sums, int Nn, int Mm, int chunk)
{
    const int g = blockIdx.x * 256 + threadIdx.x;
    const int b = g >> 10;
    const int m = g & 1023;
    const int n0 = blockIdx.y * chunk;
    const float* p = P + (long long)b * Nn * Mm + (long long)n0 * Mm + m;
    float s0 = 0.f, s1 = 0.f, s2 = 0.f, s3 = 0.f;
    for (int n = 0; n < chunk; n += 4) {
        s0 += p[(long long)(n + 0) * Mm];
        s1 += p[(long long)(n + 1) * Mm];
        s2 += p[(long long)(n + 2) * Mm];
        s3 += p[(long long)(n + 3) * Mm];
    }
    atomicAdd(&sums[g], (s0 + s1) + (s2 + s3));
}

__global__ __launch_bounds__(256) void scale_kernel(
    float* __restrict__ P, const float* __restrict__ sums)
{
    const long long base = (blockIdx.x * 256LL + threadIdx.x) * 4;
    const int b = (int)(base >> 20);
    const int col = (int)(base & 1023);
    float4 v = *(float4*)(P + base);
    const float4 s = *(const float4*)(sums + (b << 10) + col);
    v.x /= s.x; v.y /= s.y; v.z /= s.z; v.w /= s.w;
    *(float4*)(P + base) = v;
}

// ---------------------------------------------------------------------------
extern "C" void kernel_launch(void* const* d_in, const int* in_sizes, int n_in,
                              void* d_out, int out_size, void* d_ws, size_t ws_size,
                              hipStream_t stream)
{
    const int B = 8, N = 1024, ME = 1024, D = 1024;
    const float* z = (const float*)d_in[0];   // [B,N,D]
    const float* e = (const float*)d_in[1];   // [B,ME,D]
    const float* M = (const float*)d_in[2];   // [D,D]
    float* out   = (float*)d_out;
    float* e_out = out;                         // [B,N,D]
    float* Aout  = out + (long long)B * N * D;  // [B,N,ME]; holds P then A

    const size_t MB = 1024 * 1024;
    const size_t NEEDED = 100 * MB + (size_t)B * ME * sizeof(float);

    if (ws_size >= NEEDED) {
        char* W = (char*)d_ws;
        __bf16* z_hi  = (__bf16*)(W);
        __bf16* z_lo  = (__bf16*)(W + 16 * MB);
        __bf16* e_hi  = (__bf16*)(W + 32 * MB);
        __bf16* e_lo  = (__bf16*)(W + 48 * MB);
        __bf16* MT_hi = (__bf16*)(W + 64 * MB);
        __bf16* MT_lo = (__bf16*)(W + 66 * MB);
        __bf16* zM_hi = (__bf16*)(W + 68 * MB);
        __bf16* zM_lo = (__bf16*)(W + 84 * MB);
        float*  sums  = (float*)(W + 100 * MB);
        __bf16* A_bf  = z_hi;   // reused after GEMM1 consumes z
        __bf16* eT    = z_lo;   // reused after GEMM1 consumes z

        hipMemsetAsync(sums, 0, (size_t)B * ME * sizeof(float), stream);

        // Prep: z split + M transpose-split.
        split2_kernel<<<dim3((B * N * D / 4) / 256), 256, 0, stream>>>(z, z_hi, z_lo);
        transpose_split_kernel<<<dim3(D / 32, D / 32, 1), 256, 0, stream>>>(
            M, MT_hi, MT_lo, D, D, 1);

        // GEMM1: zM = z @ M  (NT vs M^T), split in + split bf16 out. [8192x1024x1024]
        mfma_gemm_nt<1, 2><<<dim3(D / 128, (B * N) / 128, 1), 256, 0, stream>>>(
            z_hi, z_lo, MT_hi, MT_lo, nullptr, zM_hi, zM_lo, nullptr, 0, 0, 0, D, D);

        // e split (hi/lo) + fused bf16 transpose (eT for GEMM3). z regions now free.
        splitT_e_kernel<<<dim3(D / 64, ME / 64, B), 256, 0, stream>>>(
            e, e_hi, e_lo, eT, ME, D);

        // GEMM2: P = exp(sigmoid(zM @ e^T)), fp32 to Aout, fused column sums.
        mfma_gemm_nt<1, 1><<<dim3(ME / 128, N / 128, B), 256, 0, stream>>>(
            zM_hi, zM_lo, e_hi, e_lo, Aout, nullptr, nullptr, sums,
            (long long)N * D, (long long)ME * D, (long long)N * ME, ME, D);

        // Softmax scale: A = P / colsum (in place) + bf16 A for GEMM3.
        scale2_kernel<<<dim3((B * N * ME / 4) / 256), 256, 0, stream>>>(Aout, sums, A_bf);

        // GEMM3: e_out = A @ e per batch (NT vs eT), plain bf16.
        mfma_gemm_nt<0, 0><<<dim3(D / 128, N / 128, B), 256, 0, stream>>>(
            A_bf, nullptr, eT, nullptr, e_out, nullptr, nullptr, nullptr,
            (long long)N * ME, (long long)D * ME, (long long)N * D, D, ME);
    } else {
        // fp32 fallback (round-1 path), needs 32 MB + 32 KB.
        float* zM   = (float*)d_ws;
        float* sums = (float*)((char*)d_ws + (size_t)B * N * D * 4);
        gemm_kernel<false, 0><<<dim3(ME / TILE, (B * N) / TILE, 1), 256, 0, stream>>>(
            z, M, zM, 0, 0, 0, B * N, D, D);
        gemm_kernel<true, 1><<<dim3(ME / TILE, N / TILE, B), 256, 0, stream>>>(
            zM, e, Aout, (long long)N * D, (long long)ME * D, (long long)N * ME, N, ME, D);
        hipMemsetAsync(sums, 0, (size_t)B * ME * sizeof(float), stream);
        colsum_kernel<<<dim3((B * ME) / 256, 8), 256, 0, stream>>>(Aout, sums, N, ME, N / 8);
        scale_kernel<<<dim3((B * N * ME / 4) / 256), 256, 0, stream>>>(Aout, sums);
        gemm_kernel<false, 0><<<dim3(D / TILE, N / TILE, B), 256, 0, stream>>>(
            Aout, e, e_out, (long long)N * ME, (long long)ME * D, (long long)N * D, N, D, ME);
    }
}